// Round 12
// baseline (1599.223 us; speedup 1.0000x reference)
//
#include <hip/hip_runtime.h>
#include <math.h>

#define LW  512

typedef unsigned short u16;
typedef float f32x4 __attribute__((ext_vector_type(4)));
typedef u16 u16x4 __attribute__((ext_vector_type(4)));
typedef u16 u16x8 __attribute__((ext_vector_type(8)));
typedef unsigned u32x2v __attribute__((ext_vector_type(2)));
typedef __bf16 bf16x8 __attribute__((ext_vector_type(8)));

__device__ __forceinline__ u16 f2bf(float f) {
    return __builtin_bit_cast(u16, (__bf16)f);   // native RNE convert (proven R11)
}
__device__ __forceinline__ float bf2f(u16 h) {
    unsigned u = ((unsigned)h) << 16;
    return __builtin_bit_cast(float, u);
}
__device__ __forceinline__ float sigm(float x) {
    return __builtin_amdgcn_rcpf(1.0f + __expf(-x));
}
__device__ __forceinline__ float tanhfast(float x) {
    return 1.0f - 2.0f * __builtin_amdgcn_rcpf(1.0f + __expf(2.0f * x));
}
__device__ __forceinline__ f32x4 mfma16(u16x8 a, u16x8 b, f32x4 c) {
    return __builtin_amdgcn_mfma_f32_16x16x32_bf16(
        __builtin_bit_cast(bf16x8, a), __builtin_bit_cast(bf16x8, b), c, 0, 0, 0);
}
__device__ __forceinline__ unsigned ld_sys(const unsigned* p) {
    return __hip_atomic_load(p, __ATOMIC_RELAXED, __HIP_MEMORY_SCOPE_SYSTEM);
}
__device__ __forceinline__ void st_sys(unsigned* p, unsigned v) {
    __hip_atomic_store(p, v, __ATOMIC_RELAXED, __HIP_MEMORY_SCOPE_SYSTEM);
}
__device__ __forceinline__ void poll_ge(const unsigned* p, unsigned want) {
    while (ld_sys(p) < want) __builtin_amdgcn_s_sleep(2);
    asm volatile("" ::: "memory");
    __builtin_amdgcn_sched_barrier(0);
}
__device__ __forceinline__ void poll4(const unsigned* p, unsigned want) {
    for (;;) {
        unsigned m0 = ld_sys(p + 0), m1 = ld_sys(p + 1);
        unsigned m2 = ld_sys(p + 2), m3 = ld_sys(p + 3);
        unsigned a = m0 < m1 ? m0 : m1;
        unsigned b = m2 < m3 ? m2 : m3;
        if ((a < b ? a : b) >= want) break;
        __builtin_amdgcn_s_sleep(2);
    }
    asm volatile("" ::: "memory");
    __builtin_amdgcn_sched_barrier(0);
}
__device__ __forceinline__ void bar_lgkm() {
    asm volatile("s_waitcnt lgkmcnt(0)" ::: "memory");
    __builtin_amdgcn_s_barrier();
}

// ---- sort lane exchanges (R9/R11-PROVEN set; permlane permanently banned) ----
template<int CTRL> __device__ __forceinline__ float dppf(float v) {
    return __builtin_bit_cast(float,
        __builtin_amdgcn_mov_dpp(__builtin_bit_cast(int, v), CTRL, 0xF, 0xF, false));
}
template<int OFF> __device__ __forceinline__ float swzf(float v) {
    return __builtin_bit_cast(float,
        __builtin_amdgcn_ds_swizzle(__builtin_bit_cast(int, v), OFF));
}
template<int J> __device__ __forceinline__ float xch(float v) {
    if constexpr (J == 1)  return dppf<0xB1>(v);        // quad_perm [1,0,3,2]
    else if constexpr (J == 2)  return dppf<0x4E>(v);   // quad_perm [2,3,0,1]
    else if constexpr (J == 4)  return swzf<0x101F>(v); // bit-mode xor4
    else if constexpr (J == 8)  return swzf<0x201F>(v); // bit-mode xor8
    else if constexpr (J == 16) return swzf<0x401F>(v); // bit-mode xor16
    else return __shfl_xor(v, 32);
}
#define STG4(KK, J) { \
    float o0 = xch<J>(v0), o1 = xch<J>(v1), o2 = xch<J>(v2), o3 = xch<J>(v3); \
    bool k = (((ln & KK) == 0) == ((ln & J) == 0)); \
    v0 = k ? fminf(v0, o0) : fmaxf(v0, o0); \
    v1 = k ? fminf(v1, o1) : fmaxf(v1, o1); \
    v2 = k ? fminf(v2, o2) : fmaxf(v2, o2); \
    v3 = k ? fminf(v3, o3) : fmaxf(v3, o3); }

// zero counters
__global__ __launch_bounds__(256) void init_flags(unsigned* f) {
    f[blockIdx.x * 256 + threadIdx.x] = 0u;
}

// ---------------- prep: fused attention matrix A = (I4⊗W3)·Π·(I4⊗W2)·Π·(I2⊗W1) ----------------
// Uses the SAME verified permutation src(g) = (g&3)*32 + (g>>2) as the kernel scatters.
__global__ __launch_bounds__(128) void prep_A(
    const float* __restrict__ aw1, const float* __restrict__ aw2,
    const float* __restrict__ aw3, u16* __restrict__ Abf)
{
    const int l   = blockIdx.x;
    const int tid = threadIdx.x;
    __shared__ float T1[128][65];
    __shared__ float T2[128][65];
    for (int ch = 0; ch < 2; ++ch) {
        for (int i = tid; i < 128 * 64; i += 128) {
            int f = i >> 6, j = i & 63;
            int s = ch * 64 + j;
            T1[f][j] = ((f >> 6) == (s >> 6))
                       ? aw1[l * 4096 + (f & 63) * 64 + (s & 63)] : 0.f;
        }
        __syncthreads();
        for (int i = tid; i < 128 * 64; i += 128) {
            int gg = i >> 6, j = i & 63;
            int n = gg & 31, r = gg >> 5;
            float acc = 0.f;
            #pragma unroll 8
            for (int k = 0; k < 32; ++k) {
                int g = r * 32 + k;
                int src = (g & 3) * 32 + (g >> 2);
                acc += aw2[l * 1024 + n * 32 + k] * T1[src][j];
            }
            T2[gg][j] = acc;
        }
        __syncthreads();
        for (int i = tid; i < 128 * 64; i += 128) {
            int ff = i >> 6, j = i & 63;
            int n = ff & 31, r = ff >> 5;
            float acc = 0.f;
            #pragma unroll 8
            for (int k = 0; k < 32; ++k) {
                int g = r * 32 + k;
                int src = (g & 3) * 32 + (g >> 2);
                acc += aw3[l * 1024 + n * 32 + k] * T2[src][j];
            }
            Abf[((size_t)l * 128 + ff) * 128 + ch * 64 + j] = f2bf(acc);
        }
        __syncthreads();
    }
}

// ---------------- recurrence: (layer, batch-group) per block ----------------
// R11-proven primitives. Fused attention: P3/P4/P5 -> single 8x128x128 GEMM.
// P2: waves 0,1 sort (4 rows each); waves 2,3 commit+prefetch. 4 barriers/step.
__global__ __launch_bounds__(256, 1) void rnn_kernel(
    const float* __restrict__ x, const float* __restrict__ h0,
    const float* __restrict__ w_ih, const float* __restrict__ w_hh,
    const float* __restrict__ bih, const float* __restrict__ bhh,
    const u16* __restrict__ Abf, const float* __restrict__ aw4,
    float* __restrict__ ys, float* __restrict__ hfin,
    unsigned* __restrict__ flags, unsigned* __restrict__ ring32, int D)
{
    const int l   = blockIdx.x >> 3;   // layer 0..7
    const int g   = blockIdx.x & 7;    // batch group 0..7
    const int bb0 = g * 8;
    const int tid = threadIdx.x;
    const int w   = tid >> 6;          // wave 0..3
    const int ln  = tid & 63;
    const int l15 = ln & 15;
    const int l4  = ln >> 4;
    const bool bp = (D < LW);

    unsigned* myflag = flags + (size_t)(l * 8 + g) * 32;         // [4] per-wave
    unsigned* pflag  = flags + (size_t)((l - 1) * 8 + g) * 32;
    unsigned* myccnt = flags + 4096 + (size_t)(l * 8 + g) * 32;
    unsigned* nccnt  = flags + 4096 + (size_t)((l + 1) * 8 + g) * 32;

    __shared__ __align__(16) u16 Hin[2][16][72]; // dbl-buffered layer input, rows 8..15 zero
    __shared__ __align__(16) u16 hbf[16][72];    // h state (bf16), rows 8..15 zero
    __shared__ __align__(16) u16 seF[16][136];   // row b: cols 0..63 = h, 64..127 = sorted; rows 8..15 zero
    __shared__ __align__(16) u16 w4A[16][136];   // relu(A·se_flat) flat 128, rows 8..15 zero

    for (int i = tid; i < 16 * 72; i += 256) {
        int r = i / 72, c = i % 72;
        if (r >= 8) { Hin[0][r][c] = 0; Hin[1][r][c] = 0; hbf[r][c] = 0; }
    }
    for (int i = tid; i < 16 * 136; i += 256) {
        int r = i / 136;
        if (r >= 8) { w4A[r][i % 136] = 0; seF[r][i % 136] = 0; }
    }

    // ---- weight B-fragments into VGPRs (t-invariant) ----
    const int o = 16 * w + l15;
    auto ldw8 = [](const float* p) {
        float4 v0 = *(const float4*)p;
        float4 v1 = *(const float4*)(p + 4);
        u16x8 r;
        r[0] = f2bf(v0.x); r[1] = f2bf(v0.y); r[2] = f2bf(v0.z); r[3] = f2bf(v0.w);
        r[4] = f2bf(v1.x); r[5] = f2bf(v1.y); r[6] = f2bf(v1.z); r[7] = f2bf(v1.w);
        return r;
    };
    const float* ih = w_ih + l * 12288;
    const float* hh = w_hh + l * 12288;
    u16x8 Br[4], Bz[4], Bni[2], Bnh[2], B4f[4], BA[2][4];
    Br[0] = ldw8(ih + o * 64 + l4 * 8);        Br[1] = ldw8(ih + o * 64 + 32 + l4 * 8);
    Br[2] = ldw8(hh + o * 64 + l4 * 8);        Br[3] = ldw8(hh + o * 64 + 32 + l4 * 8);
    Bz[0] = ldw8(ih + (64 + o) * 64 + l4 * 8); Bz[1] = ldw8(ih + (64 + o) * 64 + 32 + l4 * 8);
    Bz[2] = ldw8(hh + (64 + o) * 64 + l4 * 8); Bz[3] = ldw8(hh + (64 + o) * 64 + 32 + l4 * 8);
    Bni[0] = ldw8(ih + (128 + o) * 64 + l4 * 8); Bni[1] = ldw8(ih + (128 + o) * 64 + 32 + l4 * 8);
    Bnh[0] = ldw8(hh + (128 + o) * 64 + l4 * 8); Bnh[1] = ldw8(hh + (128 + o) * 64 + 32 + l4 * 8);
    #pragma unroll
    for (int kk = 0; kk < 4; ++kk)
        B4f[kk] = ldw8(aw4 + l * 8192 + o * 128 + kk * 32 + l4 * 8);
    #pragma unroll
    for (int nt = 0; nt < 2; ++nt)
        #pragma unroll
        for (int kk = 0; kk < 4; ++kk)
            BA[nt][kk] = *(const u16x8*)&Abf[((size_t)l * 128 + (16 * (2 * w + nt) + l15)) * 128
                                             + kk * 32 + l4 * 8];

    const float brs  = bih[l * 192 + o]       + bhh[l * 192 + o];
    const float bzs  = bih[l * 192 + 64 + o]  + bhh[l * 192 + 64 + o];
    const float bnis = bih[l * 192 + 128 + o];
    const float bnhs = bhh[l * 192 + 128 + o];

    float hreg[4];
    {
        float hv = h0[l * 64 + o];
        #pragma unroll
        for (int j = 0; j < 4; ++j) hreg[j] = hv;
        if (l4 < 2) {
            u16 hb = f2bf(hv);
            #pragma unroll
            for (int j = 0; j < 4; ++j) hbf[l4 * 4 + j][o] = hb;
        }
    }

    // ---- prologue: stage slot 0 into Hin[0]; slot 1 into stash regs ----
    float4 stf = {0.f, 0.f, 0.f, 0.f};
    unsigned st0 = 0, st1 = 0;
    if (w >= 2) {
        const int rr = (tid - 128) >> 4, c4 = ((tid - 128) & 15) * 4;
        if (l == 0) {
            float4 a = *(const float4*)(x + (size_t)(bb0 + rr) * 32768 + c4);
            u16x4 hv;
            hv[0] = f2bf(a.x); hv[1] = f2bf(a.y); hv[2] = f2bf(a.z); hv[3] = f2bf(a.w);
            *(u16x4*)&Hin[0][rr][c4] = hv;
            stf = *(const float4*)(x + (size_t)(bb0 + rr) * 32768 + 64 + c4);
        } else {
            poll4(pflag, 1u);
            const unsigned* sp0 = ring32 + ((size_t)((l - 1) * 8 + g) * D + 0) * 256 + rr * 32 + (c4 >> 1);
            unsigned a0 = ld_sys(sp0), a1 = ld_sys(sp0 + 1);
            u32x2v dv = {a0, a1};
            *(u16x4*)&Hin[0][rr][c4] = __builtin_bit_cast(u16x4, dv);
            poll4(pflag, 2u);
            const unsigned* sp1 = ring32 + ((size_t)((l - 1) * 8 + g) * D + 1) * 256 + rr * 32 + (c4 >> 1);
            st0 = ld_sys(sp1); st1 = ld_sys(sp1 + 1);
        }
    }
    __syncthreads();

    // prefetched A-fragments of Hin for the upcoming P1
    u16x8 pAg0 = *(const u16x8*)&Hin[0][l15][l4 * 8];
    u16x8 pAg1 = *(const u16x8*)&Hin[0][l15][32 + l4 * 8];

    for (int t = 0; t < LW; ++t) {
        float hg[4];
        // ================= P1: GRU =================
        {
            u16x8 Ah0 = *(const u16x8*)&hbf[l15][l4 * 8];
            u16x8 Ah1 = *(const u16x8*)&hbf[l15][32 + l4 * 8];
            f32x4 z4 = {0.f, 0.f, 0.f, 0.f};
            f32x4 aR = z4, aZ = z4, aNI = z4, aNH = z4;
            aR = mfma16(pAg0, Br[0], aR);  aR = mfma16(pAg1, Br[1], aR);
            aR = mfma16(Ah0, Br[2], aR);   aR = mfma16(Ah1, Br[3], aR);
            aZ = mfma16(pAg0, Bz[0], aZ);  aZ = mfma16(pAg1, Bz[1], aZ);
            aZ = mfma16(Ah0, Bz[2], aZ);   aZ = mfma16(Ah1, Bz[3], aZ);
            aNI = mfma16(pAg0, Bni[0], aNI); aNI = mfma16(pAg1, Bni[1], aNI);
            aNH = mfma16(Ah0, Bnh[0], aNH);  aNH = mfma16(Ah1, Bnh[1], aNH);
            #pragma unroll
            for (int j = 0; j < 4; ++j) {
                float r  = sigm(aR[j] + brs);
                float zz = sigm(aZ[j] + bzs);
                float nn = tanhfast(aNI[j] + bnis + r * (aNH[j] + bnhs));
                hg[j] = (1.0f - zz) * nn + zz * hreg[j];
            }
            if (l4 < 2) {
                #pragma unroll
                for (int j = 0; j < 4; ++j) seF[l4 * 4 + j][o] = f2bf(hg[j]);
            }
        }
        bar_lgkm();   // P1e

        // ===== P2: waves 0,1 sort 4 rows each; waves 2,3 commit stash + prefetch =====
        if (w < 2) {
            const int r0 = 4 * w;
            float v0 = bf2f(seF[r0 + 0][ln]);
            float v1 = bf2f(seF[r0 + 1][ln]);
            float v2 = bf2f(seF[r0 + 2][ln]);
            float v3 = bf2f(seF[r0 + 3][ln]);
            STG4(2, 1)
            STG4(4, 2)  STG4(4, 1)
            STG4(8, 4)  STG4(8, 2)  STG4(8, 1)
            STG4(16, 8) STG4(16, 4) STG4(16, 2) STG4(16, 1)
            STG4(32, 16) STG4(32, 8) STG4(32, 4) STG4(32, 2) STG4(32, 1)
            STG4(64, 32) STG4(64, 16) STG4(64, 8) STG4(64, 4) STG4(64, 2) STG4(64, 1)
            seF[r0 + 0][64 + ln] = f2bf(v0);
            seF[r0 + 1][64 + ln] = f2bf(v1);
            seF[r0 + 2][64 + ln] = f2bf(v2);
            seF[r0 + 3][64 + ln] = f2bf(v3);
        } else {
            const int rr = (tid - 128) >> 4, c4 = ((tid - 128) & 15) * 4;
            if (t + 1 < LW) {     // commit stash (slot t+1) -> Hin[(t+1)&1]
                u16x4 hv;
                if (l == 0) {
                    hv[0] = f2bf(stf.x); hv[1] = f2bf(stf.y);
                    hv[2] = f2bf(stf.z); hv[3] = f2bf(stf.w);
                } else {
                    u32x2v dv = {st0, st1};
                    hv = __builtin_bit_cast(u16x4, dv);
                }
                *(u16x4*)&Hin[(t + 1) & 1][rr][c4] = hv;
            }
            if (t + 2 < LW) {     // issue loads for slot t+2
                if (l == 0) {
                    stf = *(const float4*)(x + (size_t)(bb0 + rr) * 32768 + (t + 2) * 64 + c4);
                } else {
                    poll4(pflag, (unsigned)(t + 3));
                    const unsigned* sp = ring32
                        + ((size_t)((l - 1) * 8 + g) * D + ((t + 2) & (D - 1))) * 256
                        + rr * 32 + (c4 >> 1);
                    st0 = ld_sys(sp); st1 = ld_sys(sp + 1);
                }
            }
        }
        bar_lgkm();   // P2e
        if (bp && l > 0 && tid == 0)
            st_sys(myccnt, (unsigned)(t + 2));   // slots <= t+1 consumed

        // ===== P35: deferred flag publish + fused attention GEMM (all waves) =====
        if (l < 7) {
            asm volatile("s_waitcnt vmcnt(0)" ::: "memory");
            if (ln == 0) st_sys(myflag + w, (unsigned)t);
        }
        {
            u16x8 As0 = *(const u16x8*)&seF[l15][l4 * 8];
            u16x8 As1 = *(const u16x8*)&seF[l15][32 + l4 * 8];
            u16x8 As2 = *(const u16x8*)&seF[l15][64 + l4 * 8];
            u16x8 As3 = *(const u16x8*)&seF[l15][96 + l4 * 8];
            f32x4 z4 = {0.f, 0.f, 0.f, 0.f};
            f32x4 c0 = z4, c1 = z4;
            c0 = mfma16(As0, BA[0][0], c0); c0 = mfma16(As1, BA[0][1], c0);
            c0 = mfma16(As2, BA[0][2], c0); c0 = mfma16(As3, BA[0][3], c0);
            c1 = mfma16(As0, BA[1][0], c1); c1 = mfma16(As1, BA[1][1], c1);
            c1 = mfma16(As2, BA[1][2], c1); c1 = mfma16(As3, BA[1][3], c1);
            if (l4 < 2) {
                #pragma unroll
                for (int j = 0; j < 4; ++j) {
                    int m = l4 * 4 + j;
                    w4A[m][16 * (2 * w + 0) + l15] = f2bf(fmaxf(c0[j], 0.0f));
                    w4A[m][16 * (2 * w + 1) + l15] = f2bf(fmaxf(c1[j], 0.0f));
                }
            }
        }
        bar_lgkm();   // P5e

        // ================= P6: scores + h update + publish =================
        {
            u16x8 A40 = *(const u16x8*)&w4A[l15][l4 * 8];
            u16x8 A41 = *(const u16x8*)&w4A[l15][32 + l4 * 8];
            u16x8 A42 = *(const u16x8*)&w4A[l15][64 + l4 * 8];
            u16x8 A43 = *(const u16x8*)&w4A[l15][96 + l4 * 8];
            // prefetch next step's input fragments (committed in P2, stable after P2e)
            pAg0 = *(const u16x8*)&Hin[(t + 1) & 1][l15][l4 * 8];
            pAg1 = *(const u16x8*)&Hin[(t + 1) & 1][l15][32 + l4 * 8];
            f32x4 cs = {0.f, 0.f, 0.f, 0.f};
            cs = mfma16(A40, B4f[0], cs);
            cs = mfma16(A41, B4f[1], cs);
            cs = mfma16(A42, B4f[2], cs);
            cs = mfma16(A43, B4f[3], cs);

            if (bp && l < 7 && t >= D) {
                poll_ge(nccnt, (unsigned)(t - D + 1));
            }
            unsigned* slotp = ring32 + ((size_t)(l * 8 + g) * D + (t & (D - 1))) * 256;
            float hn[4]; u16 hb[4];
            #pragma unroll
            for (int j = 0; j < 4; ++j) {
                hn[j] = hg[j] * sigm(cs[j]);
                hreg[j] = hn[j];
                hb[j] = f2bf(hn[j]);
            }
            if (l4 < 2) {
                #pragma unroll
                for (int j = 0; j < 4; ++j) {
                    int row = l4 * 4 + j;
                    hbf[row][o] = hb[j];
                    if (l == 7) ys[(((size_t)(bb0 + row) << 9) + t) * 64 + o] = hn[j];
                    if (t == 511) hfin[((l << 6) + bb0 + row) * 64 + o] = hn[j];
                }
            }
            if (l < 7) {
                #pragma unroll
                for (int j = 0; j < 4; ++j) {
                    unsigned ob = (unsigned)__shfl_xor((int)(unsigned)hb[j], 1) & 0xffffu;
                    if (l4 < 2 && !(l15 & 1)) {
                        unsigned word = (unsigned)hb[j] | (ob << 16);
                        st_sys(&slotp[(l4 * 4 + j) * 32 + (o >> 1)], word);
                    }
                }
            }
        }
        bar_lgkm();   // P6e (lgkm only; ring stores drain in background)
    }

    // epilogue: final flag so consumer's last prefetches can complete
    if (l < 7) {
        asm volatile("s_waitcnt vmcnt(0)" ::: "memory");
        if (ln == 0) st_sys(myflag + w, 512u);
    }
}

// ---------------- heads: per-window seg + cls logits ----------------
__global__ __launch_bounds__(256) void heads_kernel(
    const float* __restrict__ ys,
    const float* __restrict__ sw1, const float* __restrict__ sb1,
    const float* __restrict__ sw2, const float* __restrict__ sb2,
    const float* __restrict__ sw3, const float* __restrict__ sb3,
    const float* __restrict__ sw4, const float* __restrict__ sb4,
    const float* __restrict__ cw1, const float* __restrict__ cb1,
    const float* __restrict__ cw2, const float* __restrict__ cb2,
    const float* __restrict__ cw3, const float* __restrict__ cb3,
    const float* __restrict__ cw4, const float* __restrict__ cb4,
    float* __restrict__ seg_out, float* __restrict__ cls_tmp)
{
    const int idx = blockIdx.x * 256 + threadIdx.x;
    if (idx >= 64 * LW) return;
    const int b = idx >> 9, t = idx & 511;

    float y[64];
    const float4* yp = (const float4*)(ys + (size_t)idx * 64);
    #pragma unroll
    for (int i = 0; i < 16; ++i) {
        float4 v = yp[i];
        y[4 * i + 0] = v.x; y[4 * i + 1] = v.y; y[4 * i + 2] = v.z; y[4 * i + 3] = v.w;
    }

    float t1[8][4], t2[8][4], t3[8][4];

    // ======== seg head ========
    #pragma unroll
    for (int g = 0; g < 8; ++g)
        #pragma unroll
        for (int s = 0; s < 4; ++s) {
            float acc = sb1[s];
            #pragma unroll
            for (int k = 0; k < 8; ++k) acc = fmaf(y[g * 8 + k], sw1[s * 8 + k], acc);
            t1[g][s] = acc;
        }
    #pragma unroll
    for (int i = 0; i < 8; ++i) {
        float sh[4];
        #pragma unroll
        for (int j = 0; j < 4; ++j) { int m = i * 4 + j; sh[j] = t1[m & 7][m >> 3]; }
        #pragma unroll
        for (int s = 0; s < 4; ++s) {
            float acc = sb2[s];
            #pragma unroll
            for (int j = 0; j < 4; ++j) acc = fmaf(sh[j], sw2[s * 4 + j], acc);
            t2[i][s] = acc;
        }
    }
    #pragma unroll
    for (int i = 0; i < 8; ++i) {
        float sh[4];
        #pragma unroll
        for (int j = 0; j < 4; ++j) { int m = i * 4 + j; sh[j] = t2[m & 7][m >> 3]; }
        #pragma unroll
        for (int s = 0; s < 4; ++s) {
            float acc = sb3[s];
            #pragma unroll
            for (int j = 0; j < 4; ++j) acc = fmaf(sh[j], sw3[s * 4 + j], acc);
            t3[i][s] = acc;
        }
    }
    #pragma unroll
    for (int w = 0; w < 16; ++w) {
        float o4[4];
        #pragma unroll
        for (int s = 0; s < 4; ++s) {
            float acc = sb4[w];
            #pragma unroll
            for (int j = 0; j < 8; ++j) {
                int f = s * 8 + j;
                acc = fmaf(t3[f >> 2][f & 3], sw4[w * 8 + j], acc);
            }
            o4[s] = acc;
        }
        float4 vv = {o4[0], o4[1], o4[2], o4[3]};
        ((float4*)seg_out)[b * 8192 + t * 16 + w] = vv;
    }

    // ======== cls head ========
    #pragma unroll
    for (int g = 0; g < 8; ++g)
        #pragma unroll
        for (int s = 0; s < 4; ++s) {
            float acc = cb1[s];
            #pragma unroll
            for (int k = 0; k < 8; ++k) acc = fmaf(y[g * 8 + k], cw1[s * 8 + k], acc);
            t1[g][s] = acc;
        }
    #pragma unroll
    for (int i = 0; i < 8; ++i) {
        float sh[4];
        #pragma unroll
        for (int j = 0; j < 4; ++j) { int m = i * 4 + j; sh[j] = t1[m & 7][m >> 3]; }
        #pragma unroll
        for (int s = 0; s < 4; ++s) {
            float acc = cb2[s];
            #pragma unroll
            for (int j = 0; j < 4; ++j) acc = fmaf(sh[j], cw2[s * 4 + j], acc);
            t2[i][s] = acc;
        }
    }
    #pragma unroll
    for (int i = 0; i < 8; ++i) {
        float sh[4];
        #pragma unroll
        for (int j = 0; j < 4; ++j) { int m = i * 4 + j; sh[j] = t2[m & 7][m >> 3]; }
        #pragma unroll
        for (int s = 0; s < 4; ++s) {
            float acc = cb3[s];
            #pragma unroll
            for (int j = 0; j < 4; ++j) acc = fmaf(sh[j], cw3[s * 4 + j], acc);
            t3[i][s] = fmaxf(acc, 0.f);
        }
    }
    float cc[4];
    #pragma unroll
    for (int c = 0; c < 4; ++c) {
        float acc = cb4[c];
        #pragma unroll
        for (int k = 0; k < 32; ++k)
            acc = fmaf(t3[k >> 2][k & 3], cw4[c * 32 + k], acc);
        cc[c] = acc;
    }
    float4 cv = {cc[0], cc[1], cc[2], cc[3]};
    ((float4*)cls_tmp)[idx] = cv;
}

// ---------------- cls mean over windows ----------------
__global__ __launch_bounds__(256) void cls_reduce_kernel(
    const float* __restrict__ cls_tmp, float* __restrict__ cls_out)
{
    const int tid = threadIdx.x;
    const int b = tid >> 2, q = tid & 3;
    float ax = 0.f, ay = 0.f, az = 0.f, aw = 0.f;
    for (int t = q; t < 512; t += 4) {
        float4 v = ((const float4*)cls_tmp)[b * 512 + t];
        ax += v.x; ay += v.y; az += v.z; aw += v.w;
    }
    ax += __shfl_xor(ax, 1); ay += __shfl_xor(ay, 1);
    az += __shfl_xor(az, 1); aw += __shfl_xor(aw, 1);
    ax += __shfl_xor(ax, 2); ay += __shfl_xor(ay, 2);
    az += __shfl_xor(az, 2); aw += __shfl_xor(aw, 2);
    if (q == 0) {
        float4 rv = {ax / 512.f, ay / 512.f, az / 512.f, aw / 512.f};
        ((float4*)cls_out)[b] = rv;
    }
}

// ---------------- avg_pool1d(k=11,s=1) with 10 zero history ----------------
__global__ __launch_bounds__(256) void pool_kernel(
    const float* __restrict__ seg, float* __restrict__ pool_out)
{
    const int idx = blockIdx.x * 256 + threadIdx.x;
    if (idx >= 64 * 8192) return;
    const int b = idx >> 13, ll = idx & 8191;
    float ax = 0.f, ay = 0.f, az = 0.f, aw = 0.f;
    int j0 = ll - 10; if (j0 < 0) j0 = 0;
    for (int j = j0; j <= ll; ++j) {
        float4 v = ((const float4*)seg)[b * 8192 + j];
        ax += v.x; ay += v.y; az += v.z; aw += v.w;
    }
    const float inv = 1.0f / 11.0f;
    float4 ov = {ax * inv, ay * inv, az * inv, aw * inv};
    ((float4*)pool_out)[idx] = ov;
}

extern "C" void kernel_launch(void* const* d_in, const int* in_sizes, int n_in,
                              void* d_out, int out_size, void* d_ws, size_t ws_size,
                              hipStream_t stream)
{
    const float* x    = (const float*)d_in[0];
    const float* h0   = (const float*)d_in[1];
    const float* w_ih = (const float*)d_in[2];
    const float* w_hh = (const float*)d_in[3];
    const float* bihp = (const float*)d_in[4];
    const float* bhhp = (const float*)d_in[5];
    const float* aw1  = (const float*)d_in[6];
    const float* aw2  = (const float*)d_in[7];
    const float* aw3  = (const float*)d_in[8];
    const float* aw4  = (const float*)d_in[9];
    const float* sw1  = (const float*)d_in[10];
    const float* sb1  = (const float*)d_in[11];
    const float* sw2  = (const float*)d_in[12];
    const float* sb2  = (const float*)d_in[13];
    const float* sw3  = (const float*)d_in[14];
    const float* sb3  = (const float*)d_in[15];
    const float* sw4  = (const float*)d_in[16];
    const float* sb4  = (const float*)d_in[17];
    const float* cw1  = (const float*)d_in[18];
    const float* cb1  = (const float*)d_in[19];
    const float* cw2  = (const float*)d_in[20];
    const float* cb2  = (const float*)d_in[21];
    const float* cw3  = (const float*)d_in[22];
    const float* cb3  = (const float*)d_in[23];
    const float* cw4  = (const float*)d_in[24];
    const float* cb4  = (const float*)d_in[25];

    float* out      = (float*)d_out;
    float* pool_out = out;                 // (64,8192,4)
    float* cls_out  = out + 2097152;       // (64,4)
    float* ys_out   = out + 2097408;       // (64,512,64)
    float* hfin     = out + 4194560;       // (8,64,64)
    float* seg_out  = out + 4227328;       // (64,8192,4)
    float* cls_tmp  = pool_out;            // staged in pool region, overwritten last

    unsigned* flags  = (unsigned*)d_ws;                        // 32 KB header
    u16*      Abf    = (u16*)((char*)d_ws + 32768);            // 8x128x128 bf16 = 256 KB
    unsigned* ring32 = (unsigned*)((char*)d_ws + 32768 + 262144);

    size_t hdr = 32768 + 262144;
    size_t slots = (ws_size > hdr) ? (ws_size - hdr) / (56ull * 256 * 4) : 8;
    int D = 512;
    if (slots < 512) {
        D = 8;
        while ((size_t)(D * 2) <= slots && D < 512) D <<= 1;
    }

    init_flags<<<32, 256, 0, stream>>>(flags);
    prep_A<<<8, 128, 0, stream>>>(aw1, aw2, aw3, Abf);
    rnn_kernel<<<64, 256, 0, stream>>>(x, h0, w_ih, w_hh, bihp, bhhp,
                                       Abf, aw4, ys_out, hfin,
                                       flags, ring32, D);
    heads_kernel<<<128, 256, 0, stream>>>(ys_out, sw1, sb1, sw2, sb2, sw3, sb3, sw4, sb4,
                                          cw1, cb1, cw2, cb2, cw3, cb3, cw4, cb4,
                                          seg_out, cls_tmp);
    cls_reduce_kernel<<<1, 256, 0, stream>>>(cls_tmp, cls_out);
    pool_kernel<<<2048, 256, 0, stream>>>(seg_out, pool_out);
}

// Round 13
// 1427.569 us; speedup vs baseline: 1.1202x; 1.1202x over previous
//
#include <hip/hip_runtime.h>
#include <math.h>

#define LW  512

typedef unsigned short u16;
typedef float f32x4 __attribute__((ext_vector_type(4)));
typedef u16 u16x4 __attribute__((ext_vector_type(4)));
typedef u16 u16x8 __attribute__((ext_vector_type(8)));
typedef unsigned u32x2v __attribute__((ext_vector_type(2)));
typedef __bf16 bf16x8 __attribute__((ext_vector_type(8)));

__device__ __forceinline__ u16 f2bf(float f) {
    return __builtin_bit_cast(u16, (__bf16)f);   // native RNE convert (proven R11)
}
__device__ __forceinline__ float bf2f(u16 h) {
    unsigned u = ((unsigned)h) << 16;
    return __builtin_bit_cast(float, u);
}
__device__ __forceinline__ float sigm(float x) {
    return __builtin_amdgcn_rcpf(1.0f + __expf(-x));
}
__device__ __forceinline__ float tanhfast(float x) {
    return 1.0f - 2.0f * __builtin_amdgcn_rcpf(1.0f + __expf(2.0f * x));
}
__device__ __forceinline__ f32x4 mfma16(u16x8 a, u16x8 b, f32x4 c) {
    return __builtin_amdgcn_mfma_f32_16x16x32_bf16(
        __builtin_bit_cast(bf16x8, a), __builtin_bit_cast(bf16x8, b), c, 0, 0, 0);
}
__device__ __forceinline__ unsigned ld_sys(const unsigned* p) {
    return __hip_atomic_load(p, __ATOMIC_RELAXED, __HIP_MEMORY_SCOPE_SYSTEM);
}
__device__ __forceinline__ void st_sys(unsigned* p, unsigned v) {
    __hip_atomic_store(p, v, __ATOMIC_RELAXED, __HIP_MEMORY_SCOPE_SYSTEM);
}
__device__ __forceinline__ void poll_ge(const unsigned* p, unsigned want) {
    while (ld_sys(p) < want) __builtin_amdgcn_s_sleep(2);
    asm volatile("" ::: "memory");
    __builtin_amdgcn_sched_barrier(0);
}
__device__ __forceinline__ void poll4(const unsigned* p, unsigned want) {
    for (;;) {
        unsigned m0 = ld_sys(p + 0), m1 = ld_sys(p + 1);
        unsigned m2 = ld_sys(p + 2), m3 = ld_sys(p + 3);
        unsigned a = m0 < m1 ? m0 : m1;
        unsigned b = m2 < m3 ? m2 : m3;
        if ((a < b ? a : b) >= want) break;
        __builtin_amdgcn_s_sleep(2);
    }
    asm volatile("" ::: "memory");
    __builtin_amdgcn_sched_barrier(0);
}
__device__ __forceinline__ void bar_lgkm() {
    asm volatile("s_waitcnt lgkmcnt(0)" ::: "memory");
    __builtin_amdgcn_s_barrier();
}

// ---- sort lane exchanges (R9/R11-PROVEN set; permlane permanently banned) ----
template<int CTRL> __device__ __forceinline__ float dppf(float v) {
    return __builtin_bit_cast(float,
        __builtin_amdgcn_mov_dpp(__builtin_bit_cast(int, v), CTRL, 0xF, 0xF, false));
}
template<int OFF> __device__ __forceinline__ float swzf(float v) {
    return __builtin_bit_cast(float,
        __builtin_amdgcn_ds_swizzle(__builtin_bit_cast(int, v), OFF));
}
template<int J> __device__ __forceinline__ float xch(float v) {
    if constexpr (J == 1)  return dppf<0xB1>(v);        // quad_perm [1,0,3,2]
    else if constexpr (J == 2)  return dppf<0x4E>(v);   // quad_perm [2,3,0,1]
    else if constexpr (J == 4)  return swzf<0x101F>(v); // bit-mode xor4
    else if constexpr (J == 8)  return swzf<0x201F>(v); // bit-mode xor8
    else if constexpr (J == 16) return swzf<0x401F>(v); // bit-mode xor16
    else return __shfl_xor(v, 32);
}
#define STG4(KK, J) { \
    float o0 = xch<J>(v0), o1 = xch<J>(v1), o2 = xch<J>(v2), o3 = xch<J>(v3); \
    bool k = (((ln & KK) == 0) == ((ln & J) == 0)); \
    v0 = k ? fminf(v0, o0) : fmaxf(v0, o0); \
    v1 = k ? fminf(v1, o1) : fmaxf(v1, o1); \
    v2 = k ? fminf(v2, o2) : fmaxf(v2, o2); \
    v3 = k ? fminf(v3, o3) : fmaxf(v3, o3); }

// zero counters
__global__ __launch_bounds__(256) void init_flags(unsigned* f) {
    f[blockIdx.x * 256 + threadIdx.x] = 0u;
}

// ---------------- prep: fused attention matrix A = (I4⊗W3)·Π·(I4⊗W2)·Π·(I2⊗W1) ----------------
__global__ __launch_bounds__(128) void prep_A(
    const float* __restrict__ aw1, const float* __restrict__ aw2,
    const float* __restrict__ aw3, u16* __restrict__ Abf)
{
    const int l   = blockIdx.x;
    const int tid = threadIdx.x;
    __shared__ float T1[128][65];
    __shared__ float T2[128][65];
    for (int ch = 0; ch < 2; ++ch) {
        for (int i = tid; i < 128 * 64; i += 128) {
            int f = i >> 6, j = i & 63;
            int s = ch * 64 + j;
            T1[f][j] = ((f >> 6) == (s >> 6))
                       ? aw1[l * 4096 + (f & 63) * 64 + (s & 63)] : 0.f;
        }
        __syncthreads();
        for (int i = tid; i < 128 * 64; i += 128) {
            int gg = i >> 6, j = i & 63;
            int n = gg & 31, r = gg >> 5;
            float acc = 0.f;
            #pragma unroll 8
            for (int k = 0; k < 32; ++k) {
                int g = r * 32 + k;
                int src = (g & 3) * 32 + (g >> 2);
                acc += aw2[l * 1024 + n * 32 + k] * T1[src][j];
            }
            T2[gg][j] = acc;
        }
        __syncthreads();
        for (int i = tid; i < 128 * 64; i += 128) {
            int ff = i >> 6, j = i & 63;
            int n = ff & 31, r = ff >> 5;
            float acc = 0.f;
            #pragma unroll 8
            for (int k = 0; k < 32; ++k) {
                int g = r * 32 + k;
                int src = (g & 3) * 32 + (g >> 2);
                acc += aw3[l * 1024 + n * 32 + k] * T2[src][j];
            }
            Abf[((size_t)l * 128 + ff) * 128 + ch * 64 + j] = f2bf(acc);
        }
        __syncthreads();
    }
}

// ---------------- recurrence: (layer, batch-group) per block ----------------
// R12 structure with ONE fix: deferred flag publish moved to TOP of P2 (before
// any VMEM issued this step) so its vmcnt(0) never drains fresh prefetch loads.
__global__ __launch_bounds__(256, 1) void rnn_kernel(
    const float* __restrict__ x, const float* __restrict__ h0,
    const float* __restrict__ w_ih, const float* __restrict__ w_hh,
    const float* __restrict__ bih, const float* __restrict__ bhh,
    const u16* __restrict__ Abf, const float* __restrict__ aw4,
    float* __restrict__ ys, float* __restrict__ hfin,
    unsigned* __restrict__ flags, unsigned* __restrict__ ring32, int D)
{
    const int l   = blockIdx.x >> 3;   // layer 0..7
    const int g   = blockIdx.x & 7;    // batch group 0..7
    const int bb0 = g * 8;
    const int tid = threadIdx.x;
    const int w   = tid >> 6;          // wave 0..3
    const int ln  = tid & 63;
    const int l15 = ln & 15;
    const int l4  = ln >> 4;
    const bool bp = (D < LW);

    unsigned* myflag = flags + (size_t)(l * 8 + g) * 32;         // [4] per-wave
    unsigned* pflag  = flags + (size_t)((l - 1) * 8 + g) * 32;
    unsigned* myccnt = flags + 4096 + (size_t)(l * 8 + g) * 32;
    unsigned* nccnt  = flags + 4096 + (size_t)((l + 1) * 8 + g) * 32;

    __shared__ __align__(16) u16 Hin[2][16][72]; // dbl-buffered layer input, rows 8..15 zero
    __shared__ __align__(16) u16 hbf[16][72];    // h state (bf16), rows 8..15 zero
    __shared__ __align__(16) u16 seF[16][136];   // row b: cols 0..63 = h, 64..127 = sorted; rows 8..15 zero
    __shared__ __align__(16) u16 w4A[16][136];   // relu(A·se_flat) flat 128, rows 8..15 zero

    for (int i = tid; i < 16 * 72; i += 256) {
        int r = i / 72, c = i % 72;
        if (r >= 8) { Hin[0][r][c] = 0; Hin[1][r][c] = 0; hbf[r][c] = 0; }
    }
    for (int i = tid; i < 16 * 136; i += 256) {
        int r = i / 136;
        if (r >= 8) { w4A[r][i % 136] = 0; seF[r][i % 136] = 0; }
    }

    // ---- weight B-fragments into VGPRs (t-invariant) ----
    const int o = 16 * w + l15;
    auto ldw8 = [](const float* p) {
        float4 v0 = *(const float4*)p;
        float4 v1 = *(const float4*)(p + 4);
        u16x8 r;
        r[0] = f2bf(v0.x); r[1] = f2bf(v0.y); r[2] = f2bf(v0.z); r[3] = f2bf(v0.w);
        r[4] = f2bf(v1.x); r[5] = f2bf(v1.y); r[6] = f2bf(v1.z); r[7] = f2bf(v1.w);
        return r;
    };
    const float* ih = w_ih + l * 12288;
    const float* hh = w_hh + l * 12288;
    u16x8 Br[4], Bz[4], Bni[2], Bnh[2], B4f[4], BA[2][4];
    Br[0] = ldw8(ih + o * 64 + l4 * 8);        Br[1] = ldw8(ih + o * 64 + 32 + l4 * 8);
    Br[2] = ldw8(hh + o * 64 + l4 * 8);        Br[3] = ldw8(hh + o * 64 + 32 + l4 * 8);
    Bz[0] = ldw8(ih + (64 + o) * 64 + l4 * 8); Bz[1] = ldw8(ih + (64 + o) * 64 + 32 + l4 * 8);
    Bz[2] = ldw8(hh + (64 + o) * 64 + l4 * 8); Bz[3] = ldw8(hh + (64 + o) * 64 + 32 + l4 * 8);
    Bni[0] = ldw8(ih + (128 + o) * 64 + l4 * 8); Bni[1] = ldw8(ih + (128 + o) * 64 + 32 + l4 * 8);
    Bnh[0] = ldw8(hh + (128 + o) * 64 + l4 * 8); Bnh[1] = ldw8(hh + (128 + o) * 64 + 32 + l4 * 8);
    #pragma unroll
    for (int kk = 0; kk < 4; ++kk)
        B4f[kk] = ldw8(aw4 + l * 8192 + o * 128 + kk * 32 + l4 * 8);
    #pragma unroll
    for (int nt = 0; nt < 2; ++nt)
        #pragma unroll
        for (int kk = 0; kk < 4; ++kk)
            BA[nt][kk] = *(const u16x8*)&Abf[((size_t)l * 128 + (16 * (2 * w + nt) + l15)) * 128
                                             + kk * 32 + l4 * 8];

    const float brs  = bih[l * 192 + o]       + bhh[l * 192 + o];
    const float bzs  = bih[l * 192 + 64 + o]  + bhh[l * 192 + 64 + o];
    const float bnis = bih[l * 192 + 128 + o];
    const float bnhs = bhh[l * 192 + 128 + o];

    float hreg[4];
    {
        float hv = h0[l * 64 + o];
        #pragma unroll
        for (int j = 0; j < 4; ++j) hreg[j] = hv;
        if (l4 < 2) {
            u16 hb = f2bf(hv);
            #pragma unroll
            for (int j = 0; j < 4; ++j) hbf[l4 * 4 + j][o] = hb;
        }
    }

    // ---- prologue: stage slot 0 into Hin[0]; slot 1 into stash regs ----
    float4 stf = {0.f, 0.f, 0.f, 0.f};
    unsigned st0 = 0, st1 = 0;
    if (w >= 2) {
        const int rr = (tid - 128) >> 4, c4 = ((tid - 128) & 15) * 4;
        if (l == 0) {
            float4 a = *(const float4*)(x + (size_t)(bb0 + rr) * 32768 + c4);
            u16x4 hv;
            hv[0] = f2bf(a.x); hv[1] = f2bf(a.y); hv[2] = f2bf(a.z); hv[3] = f2bf(a.w);
            *(u16x4*)&Hin[0][rr][c4] = hv;
            stf = *(const float4*)(x + (size_t)(bb0 + rr) * 32768 + 64 + c4);
        } else {
            poll4(pflag, 1u);
            const unsigned* sp0 = ring32 + ((size_t)((l - 1) * 8 + g) * D + 0) * 256 + rr * 32 + (c4 >> 1);
            unsigned a0 = ld_sys(sp0), a1 = ld_sys(sp0 + 1);
            u32x2v dv = {a0, a1};
            *(u16x4*)&Hin[0][rr][c4] = __builtin_bit_cast(u16x4, dv);
            poll4(pflag, 2u);
            const unsigned* sp1 = ring32 + ((size_t)((l - 1) * 8 + g) * D + 1) * 256 + rr * 32 + (c4 >> 1);
            st0 = ld_sys(sp1); st1 = ld_sys(sp1 + 1);
        }
    }
    __syncthreads();

    // prefetched A-fragments of Hin for the upcoming P1
    u16x8 pAg0 = *(const u16x8*)&Hin[0][l15][l4 * 8];
    u16x8 pAg1 = *(const u16x8*)&Hin[0][l15][32 + l4 * 8];

    for (int t = 0; t < LW; ++t) {
        float hg[4];
        // ================= P1: GRU =================
        {
            u16x8 Ah0 = *(const u16x8*)&hbf[l15][l4 * 8];
            u16x8 Ah1 = *(const u16x8*)&hbf[l15][32 + l4 * 8];
            f32x4 z4 = {0.f, 0.f, 0.f, 0.f};
            f32x4 aR = z4, aZ = z4, aNI = z4, aNH = z4;
            aR = mfma16(pAg0, Br[0], aR);  aR = mfma16(pAg1, Br[1], aR);
            aR = mfma16(Ah0, Br[2], aR);   aR = mfma16(Ah1, Br[3], aR);
            aZ = mfma16(pAg0, Bz[0], aZ);  aZ = mfma16(pAg1, Bz[1], aZ);
            aZ = mfma16(Ah0, Bz[2], aZ);   aZ = mfma16(Ah1, Bz[3], aZ);
            aNI = mfma16(pAg0, Bni[0], aNI); aNI = mfma16(pAg1, Bni[1], aNI);
            aNH = mfma16(Ah0, Bnh[0], aNH);  aNH = mfma16(Ah1, Bnh[1], aNH);
            #pragma unroll
            for (int j = 0; j < 4; ++j) {
                float r  = sigm(aR[j] + brs);
                float zz = sigm(aZ[j] + bzs);
                float nn = tanhfast(aNI[j] + bnis + r * (aNH[j] + bnhs));
                hg[j] = (1.0f - zz) * nn + zz * hreg[j];
            }
            if (l4 < 2) {
                #pragma unroll
                for (int j = 0; j < 4; ++j) seF[l4 * 4 + j][o] = f2bf(hg[j]);
            }
        }
        bar_lgkm();   // P1e

        // ===== P2 top: deferred flag publish BEFORE any VMEM issue this step =====
        // Only outstanding VMEM here = ring stores from step t-1's P6 (long acked).
        if (l < 7) {
            asm volatile("s_waitcnt vmcnt(0)" ::: "memory");
            if (ln == 0) st_sys(myflag + w, (unsigned)t);
        }
        // ===== P2: waves 0,1 sort 4 rows each; waves 2,3 commit stash + prefetch =====
        if (w < 2) {
            const int r0 = 4 * w;
            float v0 = bf2f(seF[r0 + 0][ln]);
            float v1 = bf2f(seF[r0 + 1][ln]);
            float v2 = bf2f(seF[r0 + 2][ln]);
            float v3 = bf2f(seF[r0 + 3][ln]);
            STG4(2, 1)
            STG4(4, 2)  STG4(4, 1)
            STG4(8, 4)  STG4(8, 2)  STG4(8, 1)
            STG4(16, 8) STG4(16, 4) STG4(16, 2) STG4(16, 1)
            STG4(32, 16) STG4(32, 8) STG4(32, 4) STG4(32, 2) STG4(32, 1)
            STG4(64, 32) STG4(64, 16) STG4(64, 8) STG4(64, 4) STG4(64, 2) STG4(64, 1)
            seF[r0 + 0][64 + ln] = f2bf(v0);
            seF[r0 + 1][64 + ln] = f2bf(v1);
            seF[r0 + 2][64 + ln] = f2bf(v2);
            seF[r0 + 3][64 + ln] = f2bf(v3);
        } else {
            const int rr = (tid - 128) >> 4, c4 = ((tid - 128) & 15) * 4;
            if (t + 1 < LW) {     // commit stash (slot t+1) -> Hin[(t+1)&1]
                u16x4 hv;
                if (l == 0) {
                    hv[0] = f2bf(stf.x); hv[1] = f2bf(stf.y);
                    hv[2] = f2bf(stf.z); hv[3] = f2bf(stf.w);
                } else {
                    u32x2v dv = {st0, st1};
                    hv = __builtin_bit_cast(u16x4, dv);
                }
                *(u16x4*)&Hin[(t + 1) & 1][rr][c4] = hv;
            }
            if (t + 2 < LW) {     // issue loads for slot t+2
                if (l == 0) {
                    stf = *(const float4*)(x + (size_t)(bb0 + rr) * 32768 + (t + 2) * 64 + c4);
                } else {
                    poll4(pflag, (unsigned)(t + 3));
                    const unsigned* sp = ring32
                        + ((size_t)((l - 1) * 8 + g) * D + ((t + 2) & (D - 1))) * 256
                        + rr * 32 + (c4 >> 1);
                    st0 = ld_sys(sp); st1 = ld_sys(sp + 1);
                }
            }
        }
        bar_lgkm();   // P2e
        if (bp && l > 0 && tid == 0)
            st_sys(myccnt, (unsigned)(t + 2));   // slots <= t+1 consumed

        // ===== P35: fused attention GEMM (all waves) =====
        {
            u16x8 As0 = *(const u16x8*)&seF[l15][l4 * 8];
            u16x8 As1 = *(const u16x8*)&seF[l15][32 + l4 * 8];
            u16x8 As2 = *(const u16x8*)&seF[l15][64 + l4 * 8];
            u16x8 As3 = *(const u16x8*)&seF[l15][96 + l4 * 8];
            f32x4 z4 = {0.f, 0.f, 0.f, 0.f};
            f32x4 c0 = z4, c1 = z4;
            c0 = mfma16(As0, BA[0][0], c0); c0 = mfma16(As1, BA[0][1], c0);
            c0 = mfma16(As2, BA[0][2], c0); c0 = mfma16(As3, BA[0][3], c0);
            c1 = mfma16(As0, BA[1][0], c1); c1 = mfma16(As1, BA[1][1], c1);
            c1 = mfma16(As2, BA[1][2], c1); c1 = mfma16(As3, BA[1][3], c1);
            if (l4 < 2) {
                #pragma unroll
                for (int j = 0; j < 4; ++j) {
                    int m = l4 * 4 + j;
                    w4A[m][16 * (2 * w + 0) + l15] = f2bf(fmaxf(c0[j], 0.0f));
                    w4A[m][16 * (2 * w + 1) + l15] = f2bf(fmaxf(c1[j], 0.0f));
                }
            }
        }
        bar_lgkm();   // P5e

        // ================= P6: scores + h update + publish =================
        {
            u16x8 A40 = *(const u16x8*)&w4A[l15][l4 * 8];
            u16x8 A41 = *(const u16x8*)&w4A[l15][32 + l4 * 8];
            u16x8 A42 = *(const u16x8*)&w4A[l15][64 + l4 * 8];
            u16x8 A43 = *(const u16x8*)&w4A[l15][96 + l4 * 8];
            // prefetch next step's input fragments (committed in P2, stable after P2e)
            pAg0 = *(const u16x8*)&Hin[(t + 1) & 1][l15][l4 * 8];
            pAg1 = *(const u16x8*)&Hin[(t + 1) & 1][l15][32 + l4 * 8];
            f32x4 cs = {0.f, 0.f, 0.f, 0.f};
            cs = mfma16(A40, B4f[0], cs);
            cs = mfma16(A41, B4f[1], cs);
            cs = mfma16(A42, B4f[2], cs);
            cs = mfma16(A43, B4f[3], cs);

            if (bp && l < 7 && t >= D) {
                poll_ge(nccnt, (unsigned)(t - D + 1));
            }
            unsigned* slotp = ring32 + ((size_t)(l * 8 + g) * D + (t & (D - 1))) * 256;
            float hn[4]; u16 hb[4];
            #pragma unroll
            for (int j = 0; j < 4; ++j) {
                hn[j] = hg[j] * sigm(cs[j]);
                hreg[j] = hn[j];
                hb[j] = f2bf(hn[j]);
            }
            if (l4 < 2) {
                #pragma unroll
                for (int j = 0; j < 4; ++j) {
                    int row = l4 * 4 + j;
                    hbf[row][o] = hb[j];
                    if (l == 7) ys[(((size_t)(bb0 + row) << 9) + t) * 64 + o] = hn[j];
                    if (t == 511) hfin[((l << 6) + bb0 + row) * 64 + o] = hn[j];
                }
            }
            if (l < 7) {
                #pragma unroll
                for (int j = 0; j < 4; ++j) {
                    unsigned ob = (unsigned)__shfl_xor((int)(unsigned)hb[j], 1) & 0xffffu;
                    if (l4 < 2 && !(l15 & 1)) {
                        unsigned word = (unsigned)hb[j] | (ob << 16);
                        st_sys(&slotp[(l4 * 4 + j) * 32 + (o >> 1)], word);
                    }
                }
            }
        }
        bar_lgkm();   // P6e (lgkm only; ring stores drain in background)
    }

    // epilogue: final flag so consumer's last prefetches can complete
    if (l < 7) {
        asm volatile("s_waitcnt vmcnt(0)" ::: "memory");
        if (ln == 0) st_sys(myflag + w, 512u);
    }
}

// ---------------- heads: per-window seg + cls logits ----------------
__global__ __launch_bounds__(256) void heads_kernel(
    const float* __restrict__ ys,
    const float* __restrict__ sw1, const float* __restrict__ sb1,
    const float* __restrict__ sw2, const float* __restrict__ sb2,
    const float* __restrict__ sw3, const float* __restrict__ sb3,
    const float* __restrict__ sw4, const float* __restrict__ sb4,
    const float* __restrict__ cw1, const float* __restrict__ cb1,
    const float* __restrict__ cw2, const float* __restrict__ cb2,
    const float* __restrict__ cw3, const float* __restrict__ cb3,
    const float* __restrict__ cw4, const float* __restrict__ cb4,
    float* __restrict__ seg_out, float* __restrict__ cls_tmp)
{
    const int idx = blockIdx.x * 256 + threadIdx.x;
    if (idx >= 64 * LW) return;
    const int b = idx >> 9, t = idx & 511;

    float y[64];
    const float4* yp = (const float4*)(ys + (size_t)idx * 64);
    #pragma unroll
    for (int i = 0; i < 16; ++i) {
        float4 v = yp[i];
        y[4 * i + 0] = v.x; y[4 * i + 1] = v.y; y[4 * i + 2] = v.z; y[4 * i + 3] = v.w;
    }

    float t1[8][4], t2[8][4], t3[8][4];

    // ======== seg head ========
    #pragma unroll
    for (int g = 0; g < 8; ++g)
        #pragma unroll
        for (int s = 0; s < 4; ++s) {
            float acc = sb1[s];
            #pragma unroll
            for (int k = 0; k < 8; ++k) acc = fmaf(y[g * 8 + k], sw1[s * 8 + k], acc);
            t1[g][s] = acc;
        }
    #pragma unroll
    for (int i = 0; i < 8; ++i) {
        float sh[4];
        #pragma unroll
        for (int j = 0; j < 4; ++j) { int m = i * 4 + j; sh[j] = t1[m & 7][m >> 3]; }
        #pragma unroll
        for (int s = 0; s < 4; ++s) {
            float acc = sb2[s];
            #pragma unroll
            for (int j = 0; j < 4; ++j) acc = fmaf(sh[j], sw2[s * 4 + j], acc);
            t2[i][s] = acc;
        }
    }
    #pragma unroll
    for (int i = 0; i < 8; ++i) {
        float sh[4];
        #pragma unroll
        for (int j = 0; j < 4; ++j) { int m = i * 4 + j; sh[j] = t2[m & 7][m >> 3]; }
        #pragma unroll
        for (int s = 0; s < 4; ++s) {
            float acc = sb3[s];
            #pragma unroll
            for (int j = 0; j < 4; ++j) acc = fmaf(sh[j], sw3[s * 4 + j], acc);
            t3[i][s] = acc;
        }
    }
    #pragma unroll
    for (int w = 0; w < 16; ++w) {
        float o4[4];
        #pragma unroll
        for (int s = 0; s < 4; ++s) {
            float acc = sb4[w];
            #pragma unroll
            for (int j = 0; j < 8; ++j) {
                int f = s * 8 + j;
                acc = fmaf(t3[f >> 2][f & 3], sw4[w * 8 + j], acc);
            }
            o4[s] = acc;
        }
        float4 vv = {o4[0], o4[1], o4[2], o4[3]};
        ((float4*)seg_out)[b * 8192 + t * 16 + w] = vv;
    }

    // ======== cls head ========
    #pragma unroll
    for (int g = 0; g < 8; ++g)
        #pragma unroll
        for (int s = 0; s < 4; ++s) {
            float acc = cb1[s];
            #pragma unroll
            for (int k = 0; k < 8; ++k) acc = fmaf(y[g * 8 + k], cw1[s * 8 + k], acc);
            t1[g][s] = acc;
        }
    #pragma unroll
    for (int i = 0; i < 8; ++i) {
        float sh[4];
        #pragma unroll
        for (int j = 0; j < 4; ++j) { int m = i * 4 + j; sh[j] = t1[m & 7][m >> 3]; }
        #pragma unroll
        for (int s = 0; s < 4; ++s) {
            float acc = cb2[s];
            #pragma unroll
            for (int j = 0; j < 4; ++j) acc = fmaf(sh[j], cw2[s * 4 + j], acc);
            t2[i][s] = acc;
        }
    }
    #pragma unroll
    for (int i = 0; i < 8; ++i) {
        float sh[4];
        #pragma unroll
        for (int j = 0; j < 4; ++j) { int m = i * 4 + j; sh[j] = t2[m & 7][m >> 3]; }
        #pragma unroll
        for (int s = 0; s < 4; ++s) {
            float acc = cb3[s];
            #pragma unroll
            for (int j = 0; j < 4; ++j) acc = fmaf(sh[j], cw3[s * 4 + j], acc);
            t3[i][s] = fmaxf(acc, 0.f);
        }
    }
    float cc[4];
    #pragma unroll
    for (int c = 0; c < 4; ++c) {
        float acc = cb4[c];
        #pragma unroll
        for (int k = 0; k < 32; ++k)
            acc = fmaf(t3[k >> 2][k & 3], cw4[c * 32 + k], acc);
        cc[c] = acc;
    }
    float4 cv = {cc[0], cc[1], cc[2], cc[3]};
    ((float4*)cls_tmp)[idx] = cv;
}

// ---------------- cls mean over windows ----------------
__global__ __launch_bounds__(256) void cls_reduce_kernel(
    const float* __restrict__ cls_tmp, float* __restrict__ cls_out)
{
    const int tid = threadIdx.x;
    const int b = tid >> 2, q = tid & 3;
    float ax = 0.f, ay = 0.f, az = 0.f, aw = 0.f;
    for (int t = q; t < 512; t += 4) {
        float4 v = ((const float4*)cls_tmp)[b * 512 + t];
        ax += v.x; ay += v.y; az += v.z; aw += v.w;
    }
    ax += __shfl_xor(ax, 1); ay += __shfl_xor(ay, 1);
    az += __shfl_xor(az, 1); aw += __shfl_xor(aw, 1);
    ax += __shfl_xor(ax, 2); ay += __shfl_xor(ay, 2);
    az += __shfl_xor(az, 2); aw += __shfl_xor(aw, 2);
    if (q == 0) {
        float4 rv = {ax / 512.f, ay / 512.f, az / 512.f, aw / 512.f};
        ((float4*)cls_out)[b] = rv;
    }
}

// ---------------- avg_pool1d(k=11,s=1) with 10 zero history ----------------
__global__ __launch_bounds__(256) void pool_kernel(
    const float* __restrict__ seg, float* __restrict__ pool_out)
{
    const int idx = blockIdx.x * 256 + threadIdx.x;
    if (idx >= 64 * 8192) return;
    const int b = idx >> 13, ll = idx & 8191;
    float ax = 0.f, ay = 0.f, az = 0.f, aw = 0.f;
    int j0 = ll - 10; if (j0 < 0) j0 = 0;
    for (int j = j0; j <= ll; ++j) {
        float4 v = ((const float4*)seg)[b * 8192 + j];
        ax += v.x; ay += v.y; az += v.z; aw += v.w;
    }
    const float inv = 1.0f / 11.0f;
    float4 ov = {ax * inv, ay * inv, az * inv, aw * inv};
    ((float4*)pool_out)[idx] = ov;
}

extern "C" void kernel_launch(void* const* d_in, const int* in_sizes, int n_in,
                              void* d_out, int out_size, void* d_ws, size_t ws_size,
                              hipStream_t stream)
{
    const float* x    = (const float*)d_in[0];
    const float* h0   = (const float*)d_in[1];
    const float* w_ih = (const float*)d_in[2];
    const float* w_hh = (const float*)d_in[3];
    const float* bihp = (const float*)d_in[4];
    const float* bhhp = (const float*)d_in[5];
    const float* aw1  = (const float*)d_in[6];
    const float* aw2  = (const float*)d_in[7];
    const float* aw3  = (const float*)d_in[8];
    const float* aw4  = (const float*)d_in[9];
    const float* sw1  = (const float*)d_in[10];
    const float* sb1  = (const float*)d_in[11];
    const float* sw2  = (const float*)d_in[12];
    const float* sb2  = (const float*)d_in[13];
    const float* sw3  = (const float*)d_in[14];
    const float* sb3  = (const float*)d_in[15];
    const float* sw4  = (const float*)d_in[16];
    const float* sb4  = (const float*)d_in[17];
    const float* cw1  = (const float*)d_in[18];
    const float* cb1  = (const float*)d_in[19];
    const float* cw2  = (const float*)d_in[20];
    const float* cb2  = (const float*)d_in[21];
    const float* cw3  = (const float*)d_in[22];
    const float* cb3  = (const float*)d_in[23];
    const float* cw4  = (const float*)d_in[24];
    const float* cb4  = (const float*)d_in[25];

    float* out      = (float*)d_out;
    float* pool_out = out;                 // (64,8192,4)
    float* cls_out  = out + 2097152;       // (64,4)
    float* ys_out   = out + 2097408;       // (64,512,64)
    float* hfin     = out + 4194560;       // (8,64,64)
    float* seg_out  = out + 4227328;       // (64,8192,4)
    float* cls_tmp  = pool_out;            // staged in pool region, overwritten last

    unsigned* flags  = (unsigned*)d_ws;                        // 32 KB header
    u16*      Abf    = (u16*)((char*)d_ws + 32768);            // 8x128x128 bf16 = 256 KB
    unsigned* ring32 = (unsigned*)((char*)d_ws + 32768 + 262144);

    size_t hdr = 32768 + 262144;
    size_t slots = (ws_size > hdr) ? (ws_size - hdr) / (56ull * 256 * 4) : 8;
    int D = 512;
    if (slots < 512) {
        D = 8;
        while ((size_t)(D * 2) <= slots && D < 512) D <<= 1;
    }

    init_flags<<<32, 256, 0, stream>>>(flags);
    prep_A<<<8, 128, 0, stream>>>(aw1, aw2, aw3, Abf);
    rnn_kernel<<<64, 256, 0, stream>>>(x, h0, w_ih, w_hh, bihp, bhhp,
                                       Abf, aw4, ys_out, hfin,
                                       flags, ring32, D);
    heads_kernel<<<128, 256, 0, stream>>>(ys_out, sw1, sb1, sw2, sb2, sw3, sb3, sw4, sb4,
                                          cw1, cb1, cw2, cb2, cw3, cb3, cw4, cb4,
                                          seg_out, cls_tmp);
    cls_reduce_kernel<<<1, 256, 0, stream>>>(cls_tmp, cls_out);
    pool_kernel<<<2048, 256, 0, stream>>>(seg_out, pool_out);
}

// Round 14
// 1368.808 us; speedup vs baseline: 1.1683x; 1.0429x over previous
//
#include <hip/hip_runtime.h>
#include <math.h>

#define LW  512

typedef unsigned short u16;
typedef float f32x4 __attribute__((ext_vector_type(4)));
typedef u16 u16x4 __attribute__((ext_vector_type(4)));
typedef u16 u16x8 __attribute__((ext_vector_type(8)));
typedef unsigned u32x2v __attribute__((ext_vector_type(2)));
typedef __bf16 bf16x8 __attribute__((ext_vector_type(8)));

__device__ __forceinline__ u16 f2bf(float f) {
    return __builtin_bit_cast(u16, (__bf16)f);   // native RNE convert (proven R11)
}
__device__ __forceinline__ float bf2f(u16 h) {
    unsigned u = ((unsigned)h) << 16;
    return __builtin_bit_cast(float, u);
}
__device__ __forceinline__ float sigm(float x) {
    return __builtin_amdgcn_rcpf(1.0f + __expf(-x));
}
__device__ __forceinline__ float tanhfast(float x) {
    return 1.0f - 2.0f * __builtin_amdgcn_rcpf(1.0f + __expf(2.0f * x));
}
__device__ __forceinline__ f32x4 mfma16(u16x8 a, u16x8 b, f32x4 c) {
    return __builtin_amdgcn_mfma_f32_16x16x32_bf16(
        __builtin_bit_cast(bf16x8, a), __builtin_bit_cast(bf16x8, b), c, 0, 0, 0);
}
__device__ __forceinline__ unsigned ld_sys(const unsigned* p) {
    return __hip_atomic_load(p, __ATOMIC_RELAXED, __HIP_MEMORY_SCOPE_SYSTEM);
}
__device__ __forceinline__ void st_sys(unsigned* p, unsigned v) {
    __hip_atomic_store(p, v, __ATOMIC_RELAXED, __HIP_MEMORY_SCOPE_SYSTEM);
}
__device__ __forceinline__ void poll_ge(const unsigned* p, unsigned want) {
    while (ld_sys(p) < want) __builtin_amdgcn_s_sleep(2);
    asm volatile("" ::: "memory");
    __builtin_amdgcn_sched_barrier(0);
}
__device__ __forceinline__ void poll4(const unsigned* p, unsigned want) {
    for (;;) {
        unsigned m0 = ld_sys(p + 0), m1 = ld_sys(p + 1);
        unsigned m2 = ld_sys(p + 2), m3 = ld_sys(p + 3);
        unsigned a = m0 < m1 ? m0 : m1;
        unsigned b = m2 < m3 ? m2 : m3;
        if ((a < b ? a : b) >= want) break;
        __builtin_amdgcn_s_sleep(2);
    }
    asm volatile("" ::: "memory");
    __builtin_amdgcn_sched_barrier(0);
}
__device__ __forceinline__ void bar_lgkm() {
    asm volatile("s_waitcnt lgkmcnt(0)" ::: "memory");
    __builtin_amdgcn_s_barrier();
}

// ---- sort lane exchanges ----
// J=1,2: single quad_perm DPP (proven R9+). J=4,8: COMPOSED DPP — exonerated by
// bit-identical-failure analysis (R5-R7 composed-DPP+permlane == R10 swizzle+permlane
// bit-for-bit => composed DPP computed the same values as the proven swizzle path).
// J=16: ds_swizzle (rows of 16 unreachable by DPP). J=32: __shfl_xor.
// permlane16/32_swap PERMANENTLY BANNED (4 bit-identical failures).
template<int CTRL> __device__ __forceinline__ float dppf(float v) {
    return __builtin_bit_cast(float,
        __builtin_amdgcn_mov_dpp(__builtin_bit_cast(int, v), CTRL, 0xF, 0xF, false));
}
template<int OFF> __device__ __forceinline__ float swzf(float v) {
    return __builtin_bit_cast(float,
        __builtin_amdgcn_ds_swizzle(__builtin_bit_cast(int, v), OFF));
}
template<int J> __device__ __forceinline__ float xch(float v) {
    if constexpr (J == 1)  return dppf<0xB1>(v);            // quad_perm [1,0,3,2]
    else if constexpr (J == 2)  return dppf<0x4E>(v);       // quad_perm [2,3,0,1]
    else if constexpr (J == 4)  return dppf<0x141>(dppf<0x1B>(v)); // (l^3)^7 = l^4
    else if constexpr (J == 8)  return dppf<0x140>(dppf<0x141>(v)); // (l^7)^15 = l^8
    else if constexpr (J == 16) return swzf<0x401F>(v);     // bit-mode xor16
    else return __shfl_xor(v, 32);
}
#define STG4(KK, J) { \
    float o0 = xch<J>(v0), o1 = xch<J>(v1), o2 = xch<J>(v2), o3 = xch<J>(v3); \
    bool k = (((ln & KK) == 0) == ((ln & J) == 0)); \
    v0 = k ? fminf(v0, o0) : fmaxf(v0, o0); \
    v1 = k ? fminf(v1, o1) : fmaxf(v1, o1); \
    v2 = k ? fminf(v2, o2) : fmaxf(v2, o2); \
    v3 = k ? fminf(v3, o3) : fmaxf(v3, o3); }

// zero counters
__global__ __launch_bounds__(256) void init_flags(unsigned* f) {
    f[blockIdx.x * 256 + threadIdx.x] = 0u;
}

// ---------------- prep: fused attention matrix A = (I4⊗W3)·Π·(I4⊗W2)·Π·(I2⊗W1) ----------------
__global__ __launch_bounds__(128) void prep_A(
    const float* __restrict__ aw1, const float* __restrict__ aw2,
    const float* __restrict__ aw3, u16* __restrict__ Abf)
{
    const int l   = blockIdx.x;
    const int tid = threadIdx.x;
    __shared__ float T1[128][65];
    __shared__ float T2[128][65];
    for (int ch = 0; ch < 2; ++ch) {
        for (int i = tid; i < 128 * 64; i += 128) {
            int f = i >> 6, j = i & 63;
            int s = ch * 64 + j;
            T1[f][j] = ((f >> 6) == (s >> 6))
                       ? aw1[l * 4096 + (f & 63) * 64 + (s & 63)] : 0.f;
        }
        __syncthreads();
        for (int i = tid; i < 128 * 64; i += 128) {
            int gg = i >> 6, j = i & 63;
            int n = gg & 31, r = gg >> 5;
            float acc = 0.f;
            #pragma unroll 8
            for (int k = 0; k < 32; ++k) {
                int g = r * 32 + k;
                int src = (g & 3) * 32 + (g >> 2);
                acc += aw2[l * 1024 + n * 32 + k] * T1[src][j];
            }
            T2[gg][j] = acc;
        }
        __syncthreads();
        for (int i = tid; i < 128 * 64; i += 128) {
            int ff = i >> 6, j = i & 63;
            int n = ff & 31, r = ff >> 5;
            float acc = 0.f;
            #pragma unroll 8
            for (int k = 0; k < 32; ++k) {
                int g = r * 32 + k;
                int src = (g & 3) * 32 + (g >> 2);
                acc += aw3[l * 1024 + n * 32 + k] * T2[src][j];
            }
            Abf[((size_t)l * 128 + ff) * 128 + ch * 64 + j] = f2bf(acc);
        }
        __syncthreads();
    }
}

// ---------------- recurrence: (layer, batch-group) per block ----------------
__global__ __launch_bounds__(256, 1) void rnn_kernel(
    const float* __restrict__ x, const float* __restrict__ h0,
    const float* __restrict__ w_ih, const float* __restrict__ w_hh,
    const float* __restrict__ bih, const float* __restrict__ bhh,
    const u16* __restrict__ Abf, const float* __restrict__ aw4,
    float* __restrict__ ys, float* __restrict__ hfin,
    unsigned* __restrict__ flags, unsigned* __restrict__ ring32, int D)
{
    const int l   = blockIdx.x >> 3;   // layer 0..7
    const int g   = blockIdx.x & 7;    // batch group 0..7
    const int bb0 = g * 8;
    const int tid = threadIdx.x;
    const int w   = tid >> 6;          // wave 0..3
    const int ln  = tid & 63;
    const int l15 = ln & 15;
    const int l4  = ln >> 4;
    const bool bp = (D < LW);

    unsigned* myflag = flags + (size_t)(l * 8 + g) * 32;         // [4] per-wave
    unsigned* pflag  = flags + (size_t)((l - 1) * 8 + g) * 32;
    unsigned* myccnt = flags + 4096 + (size_t)(l * 8 + g) * 32;
    unsigned* nccnt  = flags + 4096 + (size_t)((l + 1) * 8 + g) * 32;

    __shared__ __align__(16) u16 Hin[2][16][72]; // dbl-buffered layer input, rows 8..15 zero
    __shared__ __align__(16) u16 hbf[16][72];    // h state (bf16), rows 8..15 zero
    __shared__ __align__(16) u16 seF[16][136];   // row b: cols 0..63 = h, 64..127 = sorted; rows 8..15 zero
    __shared__ __align__(16) u16 w4A[16][136];   // relu(A·se_flat) flat 128, rows 8..15 zero

    for (int i = tid; i < 16 * 72; i += 256) {
        int r = i / 72, c = i % 72;
        if (r >= 8) { Hin[0][r][c] = 0; Hin[1][r][c] = 0; hbf[r][c] = 0; }
    }
    for (int i = tid; i < 16 * 136; i += 256) {
        int r = i / 136;
        if (r >= 8) { w4A[r][i % 136] = 0; seF[r][i % 136] = 0; }
    }

    // ---- weight B-fragments into VGPRs (t-invariant) ----
    const int o = 16 * w + l15;
    auto ldw8 = [](const float* p) {
        float4 v0 = *(const float4*)p;
        float4 v1 = *(const float4*)(p + 4);
        u16x8 r;
        r[0] = f2bf(v0.x); r[1] = f2bf(v0.y); r[2] = f2bf(v0.z); r[3] = f2bf(v0.w);
        r[4] = f2bf(v1.x); r[5] = f2bf(v1.y); r[6] = f2bf(v1.z); r[7] = f2bf(v1.w);
        return r;
    };
    const float* ih = w_ih + l * 12288;
    const float* hh = w_hh + l * 12288;
    u16x8 Br[4], Bz[4], Bni[2], Bnh[2], B4f[4], BA[2][4];
    Br[0] = ldw8(ih + o * 64 + l4 * 8);        Br[1] = ldw8(ih + o * 64 + 32 + l4 * 8);
    Br[2] = ldw8(hh + o * 64 + l4 * 8);        Br[3] = ldw8(hh + o * 64 + 32 + l4 * 8);
    Bz[0] = ldw8(ih + (64 + o) * 64 + l4 * 8); Bz[1] = ldw8(ih + (64 + o) * 64 + 32 + l4 * 8);
    Bz[2] = ldw8(hh + (64 + o) * 64 + l4 * 8); Bz[3] = ldw8(hh + (64 + o) * 64 + 32 + l4 * 8);
    Bni[0] = ldw8(ih + (128 + o) * 64 + l4 * 8); Bni[1] = ldw8(ih + (128 + o) * 64 + 32 + l4 * 8);
    Bnh[0] = ldw8(hh + (128 + o) * 64 + l4 * 8); Bnh[1] = ldw8(hh + (128 + o) * 64 + 32 + l4 * 8);
    #pragma unroll
    for (int kk = 0; kk < 4; ++kk)
        B4f[kk] = ldw8(aw4 + l * 8192 + o * 128 + kk * 32 + l4 * 8);
    #pragma unroll
    for (int nt = 0; nt < 2; ++nt)
        #pragma unroll
        for (int kk = 0; kk < 4; ++kk)
            BA[nt][kk] = *(const u16x8*)&Abf[((size_t)l * 128 + (16 * (2 * w + nt) + l15)) * 128
                                             + kk * 32 + l4 * 8];

    const float brs  = bih[l * 192 + o]       + bhh[l * 192 + o];
    const float bzs  = bih[l * 192 + 64 + o]  + bhh[l * 192 + 64 + o];
    const float bnis = bih[l * 192 + 128 + o];
    const float bnhs = bhh[l * 192 + 128 + o];

    float hreg[4];
    {
        float hv = h0[l * 64 + o];
        #pragma unroll
        for (int j = 0; j < 4; ++j) hreg[j] = hv;
        if (l4 < 2) {
            u16 hb = f2bf(hv);
            #pragma unroll
            for (int j = 0; j < 4; ++j) hbf[l4 * 4 + j][o] = hb;
        }
    }

    // ---- prologue: stage slot 0 into Hin[0]; slot 1 into stash regs ----
    float4 stf = {0.f, 0.f, 0.f, 0.f};
    unsigned st0 = 0, st1 = 0;
    if (w >= 2) {
        const int rr = (tid - 128) >> 4, c4 = ((tid - 128) & 15) * 4;
        if (l == 0) {
            float4 a = *(const float4*)(x + (size_t)(bb0 + rr) * 32768 + c4);
            u16x4 hv;
            hv[0] = f2bf(a.x); hv[1] = f2bf(a.y); hv[2] = f2bf(a.z); hv[3] = f2bf(a.w);
            *(u16x4*)&Hin[0][rr][c4] = hv;
            stf = *(const float4*)(x + (size_t)(bb0 + rr) * 32768 + 64 + c4);
        } else {
            poll4(pflag, 1u);
            const unsigned* sp0 = ring32 + ((size_t)((l - 1) * 8 + g) * D + 0) * 256 + rr * 32 + (c4 >> 1);
            unsigned a0 = ld_sys(sp0), a1 = ld_sys(sp0 + 1);
            u32x2v dv = {a0, a1};
            *(u16x4*)&Hin[0][rr][c4] = __builtin_bit_cast(u16x4, dv);
            poll4(pflag, 2u);
            const unsigned* sp1 = ring32 + ((size_t)((l - 1) * 8 + g) * D + 1) * 256 + rr * 32 + (c4 >> 1);
            st0 = ld_sys(sp1); st1 = ld_sys(sp1 + 1);
        }
    }
    __syncthreads();

    // prefetched A-fragments of Hin for the upcoming P1
    u16x8 pAg0 = *(const u16x8*)&Hin[0][l15][l4 * 8];
    u16x8 pAg1 = *(const u16x8*)&Hin[0][l15][32 + l4 * 8];

    for (int t = 0; t < LW; ++t) {
        float hg[4];
        // ================= P1: GRU =================
        {
            u16x8 Ah0 = *(const u16x8*)&hbf[l15][l4 * 8];
            u16x8 Ah1 = *(const u16x8*)&hbf[l15][32 + l4 * 8];
            f32x4 z4 = {0.f, 0.f, 0.f, 0.f};
            f32x4 aR = z4, aZ = z4, aNI = z4, aNH = z4;
            aR = mfma16(pAg0, Br[0], aR);  aR = mfma16(pAg1, Br[1], aR);
            aR = mfma16(Ah0, Br[2], aR);   aR = mfma16(Ah1, Br[3], aR);
            aZ = mfma16(pAg0, Bz[0], aZ);  aZ = mfma16(pAg1, Bz[1], aZ);
            aZ = mfma16(Ah0, Bz[2], aZ);   aZ = mfma16(Ah1, Bz[3], aZ);
            aNI = mfma16(pAg0, Bni[0], aNI); aNI = mfma16(pAg1, Bni[1], aNI);
            aNH = mfma16(Ah0, Bnh[0], aNH);  aNH = mfma16(Ah1, Bnh[1], aNH);
            #pragma unroll
            for (int j = 0; j < 4; ++j) {
                float r  = sigm(aR[j] + brs);
                float zz = sigm(aZ[j] + bzs);
                float nn = tanhfast(aNI[j] + bnis + r * (aNH[j] + bnhs));
                hg[j] = (1.0f - zz) * nn + zz * hreg[j];
            }
            if (l4 < 2) {
                #pragma unroll
                for (int j = 0; j < 4; ++j) seF[l4 * 4 + j][o] = f2bf(hg[j]);
            }
        }
        bar_lgkm();   // P1e

        // ===== P2 top: deferred flag publish BEFORE any VMEM issue this step =====
        if (l < 7) {
            asm volatile("s_waitcnt vmcnt(0)" ::: "memory");
            if (ln == 0) st_sys(myflag + w, (unsigned)t);
        }
        // ===== P2: waves 0,1 sort 4 rows each; waves 2,3 commit stash + prefetch =====
        if (w < 2) {
            const int r0 = 4 * w;
            float v0 = bf2f(seF[r0 + 0][ln]);
            float v1 = bf2f(seF[r0 + 1][ln]);
            float v2 = bf2f(seF[r0 + 2][ln]);
            float v3 = bf2f(seF[r0 + 3][ln]);
            STG4(2, 1)
            STG4(4, 2)  STG4(4, 1)
            STG4(8, 4)  STG4(8, 2)  STG4(8, 1)
            STG4(16, 8) STG4(16, 4) STG4(16, 2) STG4(16, 1)
            STG4(32, 16) STG4(32, 8) STG4(32, 4) STG4(32, 2) STG4(32, 1)
            STG4(64, 32) STG4(64, 16) STG4(64, 8) STG4(64, 4) STG4(64, 2) STG4(64, 1)
            seF[r0 + 0][64 + ln] = f2bf(v0);
            seF[r0 + 1][64 + ln] = f2bf(v1);
            seF[r0 + 2][64 + ln] = f2bf(v2);
            seF[r0 + 3][64 + ln] = f2bf(v3);
        } else {
            const int rr = (tid - 128) >> 4, c4 = ((tid - 128) & 15) * 4;
            if (t + 1 < LW) {     // commit stash (slot t+1) -> Hin[(t+1)&1]
                u16x4 hv;
                if (l == 0) {
                    hv[0] = f2bf(stf.x); hv[1] = f2bf(stf.y);
                    hv[2] = f2bf(stf.z); hv[3] = f2bf(stf.w);
                } else {
                    u32x2v dv = {st0, st1};
                    hv = __builtin_bit_cast(u16x4, dv);
                }
                *(u16x4*)&Hin[(t + 1) & 1][rr][c4] = hv;
            }
            if (t + 2 < LW) {     // issue loads for slot t+2
                if (l == 0) {
                    stf = *(const float4*)(x + (size_t)(bb0 + rr) * 32768 + (t + 2) * 64 + c4);
                } else {
                    poll4(pflag, (unsigned)(t + 3));
                    const unsigned* sp = ring32
                        + ((size_t)((l - 1) * 8 + g) * D + ((t + 2) & (D - 1))) * 256
                        + rr * 32 + (c4 >> 1);
                    st0 = ld_sys(sp); st1 = ld_sys(sp + 1);
                }
            }
        }
        bar_lgkm();   // P2e
        if (bp && l > 0 && tid == 0)
            st_sys(myccnt, (unsigned)(t + 2));   // slots <= t+1 consumed

        // ===== P35: fused attention GEMM (all waves) =====
        {
            u16x8 As0 = *(const u16x8*)&seF[l15][l4 * 8];
            u16x8 As1 = *(const u16x8*)&seF[l15][32 + l4 * 8];
            u16x8 As2 = *(const u16x8*)&seF[l15][64 + l4 * 8];
            u16x8 As3 = *(const u16x8*)&seF[l15][96 + l4 * 8];
            f32x4 z4 = {0.f, 0.f, 0.f, 0.f};
            f32x4 c0 = z4, c1 = z4;
            c0 = mfma16(As0, BA[0][0], c0); c0 = mfma16(As1, BA[0][1], c0);
            c0 = mfma16(As2, BA[0][2], c0); c0 = mfma16(As3, BA[0][3], c0);
            c1 = mfma16(As0, BA[1][0], c1); c1 = mfma16(As1, BA[1][1], c1);
            c1 = mfma16(As2, BA[1][2], c1); c1 = mfma16(As3, BA[1][3], c1);
            if (l4 < 2) {
                #pragma unroll
                for (int j = 0; j < 4; ++j) {
                    int m = l4 * 4 + j;
                    w4A[m][16 * (2 * w + 0) + l15] = f2bf(fmaxf(c0[j], 0.0f));
                    w4A[m][16 * (2 * w + 1) + l15] = f2bf(fmaxf(c1[j], 0.0f));
                }
            }
        }
        bar_lgkm();   // P5e

        // ================= P6: scores + h update + publish =================
        {
            u16x8 A40 = *(const u16x8*)&w4A[l15][l4 * 8];
            u16x8 A41 = *(const u16x8*)&w4A[l15][32 + l4 * 8];
            u16x8 A42 = *(const u16x8*)&w4A[l15][64 + l4 * 8];
            u16x8 A43 = *(const u16x8*)&w4A[l15][96 + l4 * 8];
            // prefetch next step's input fragments (committed in P2, stable after P2e)
            pAg0 = *(const u16x8*)&Hin[(t + 1) & 1][l15][l4 * 8];
            pAg1 = *(const u16x8*)&Hin[(t + 1) & 1][l15][32 + l4 * 8];
            f32x4 cs = {0.f, 0.f, 0.f, 0.f};
            cs = mfma16(A40, B4f[0], cs);
            cs = mfma16(A41, B4f[1], cs);
            cs = mfma16(A42, B4f[2], cs);
            cs = mfma16(A43, B4f[3], cs);

            if (bp && l < 7 && t >= D) {
                poll_ge(nccnt, (unsigned)(t - D + 1));
            }
            unsigned* slotp = ring32 + ((size_t)(l * 8 + g) * D + (t & (D - 1))) * 256;
            float hn[4]; u16 hb[4];
            #pragma unroll
            for (int j = 0; j < 4; ++j) {
                hn[j] = hg[j] * sigm(cs[j]);
                hreg[j] = hn[j];
                hb[j] = f2bf(hn[j]);
            }
            if (l4 < 2) {
                #pragma unroll
                for (int j = 0; j < 4; ++j) {
                    int row = l4 * 4 + j;
                    hbf[row][o] = hb[j];
                    if (l == 7) ys[(((size_t)(bb0 + row) << 9) + t) * 64 + o] = hn[j];
                    if (t == 511) hfin[((l << 6) + bb0 + row) * 64 + o] = hn[j];
                }
            }
            if (l < 7) {
                #pragma unroll
                for (int j = 0; j < 4; ++j) {
                    unsigned ob = (unsigned)__shfl_xor((int)(unsigned)hb[j], 1) & 0xffffu;
                    if (l4 < 2 && !(l15 & 1)) {
                        unsigned word = (unsigned)hb[j] | (ob << 16);
                        st_sys(&slotp[(l4 * 4 + j) * 32 + (o >> 1)], word);
                    }
                }
            }
        }
        bar_lgkm();   // P6e (lgkm only; ring stores drain in background)
    }

    // epilogue: final flag so consumer's last prefetches can complete
    if (l < 7) {
        asm volatile("s_waitcnt vmcnt(0)" ::: "memory");
        if (ln == 0) st_sys(myflag + w, 512u);
    }
}

// ---------------- heads: per-window seg + cls logits ----------------
__global__ __launch_bounds__(256) void heads_kernel(
    const float* __restrict__ ys,
    const float* __restrict__ sw1, const float* __restrict__ sb1,
    const float* __restrict__ sw2, const float* __restrict__ sb2,
    const float* __restrict__ sw3, const float* __restrict__ sb3,
    const float* __restrict__ sw4, const float* __restrict__ sb4,
    const float* __restrict__ cw1, const float* __restrict__ cb1,
    const float* __restrict__ cw2, const float* __restrict__ cb2,
    const float* __restrict__ cw3, const float* __restrict__ cb3,
    const float* __restrict__ cw4, const float* __restrict__ cb4,
    float* __restrict__ seg_out, float* __restrict__ cls_tmp)
{
    const int idx = blockIdx.x * 256 + threadIdx.x;
    if (idx >= 64 * LW) return;
    const int b = idx >> 9, t = idx & 511;

    float y[64];
    const float4* yp = (const float4*)(ys + (size_t)idx * 64);
    #pragma unroll
    for (int i = 0; i < 16; ++i) {
        float4 v = yp[i];
        y[4 * i + 0] = v.x; y[4 * i + 1] = v.y; y[4 * i + 2] = v.z; y[4 * i + 3] = v.w;
    }

    float t1[8][4], t2[8][4], t3[8][4];

    // ======== seg head ========
    #pragma unroll
    for (int g = 0; g < 8; ++g)
        #pragma unroll
        for (int s = 0; s < 4; ++s) {
            float acc = sb1[s];
            #pragma unroll
            for (int k = 0; k < 8; ++k) acc = fmaf(y[g * 8 + k], sw1[s * 8 + k], acc);
            t1[g][s] = acc;
        }
    #pragma unroll
    for (int i = 0; i < 8; ++i) {
        float sh[4];
        #pragma unroll
        for (int j = 0; j < 4; ++j) { int m = i * 4 + j; sh[j] = t1[m & 7][m >> 3]; }
        #pragma unroll
        for (int s = 0; s < 4; ++s) {
            float acc = sb2[s];
            #pragma unroll
            for (int j = 0; j < 4; ++j) acc = fmaf(sh[j], sw2[s * 4 + j], acc);
            t2[i][s] = acc;
        }
    }
    #pragma unroll
    for (int i = 0; i < 8; ++i) {
        float sh[4];
        #pragma unroll
        for (int j = 0; j < 4; ++j) { int m = i * 4 + j; sh[j] = t2[m & 7][m >> 3]; }
        #pragma unroll
        for (int s = 0; s < 4; ++s) {
            float acc = sb3[s];
            #pragma unroll
            for (int j = 0; j < 4; ++j) acc = fmaf(sh[j], sw3[s * 4 + j], acc);
            t3[i][s] = acc;
        }
    }
    #pragma unroll
    for (int w = 0; w < 16; ++w) {
        float o4[4];
        #pragma unroll
        for (int s = 0; s < 4; ++s) {
            float acc = sb4[w];
            #pragma unroll
            for (int j = 0; j < 8; ++j) {
                int f = s * 8 + j;
                acc = fmaf(t3[f >> 2][f & 3], sw4[w * 8 + j], acc);
            }
            o4[s] = acc;
        }
        float4 vv = {o4[0], o4[1], o4[2], o4[3]};
        ((float4*)seg_out)[b * 8192 + t * 16 + w] = vv;
    }

    // ======== cls head ========
    #pragma unroll
    for (int g = 0; g < 8; ++g)
        #pragma unroll
        for (int s = 0; s < 4; ++s) {
            float acc = cb1[s];
            #pragma unroll
            for (int k = 0; k < 8; ++k) acc = fmaf(y[g * 8 + k], cw1[s * 8 + k], acc);
            t1[g][s] = acc;
        }
    #pragma unroll
    for (int i = 0; i < 8; ++i) {
        float sh[4];
        #pragma unroll
        for (int j = 0; j < 4; ++j) { int m = i * 4 + j; sh[j] = t1[m & 7][m >> 3]; }
        #pragma unroll
        for (int s = 0; s < 4; ++s) {
            float acc = cb2[s];
            #pragma unroll
            for (int j = 0; j < 4; ++j) acc = fmaf(sh[j], cw2[s * 4 + j], acc);
            t2[i][s] = acc;
        }
    }
    #pragma unroll
    for (int i = 0; i < 8; ++i) {
        float sh[4];
        #pragma unroll
        for (int j = 0; j < 4; ++j) { int m = i * 4 + j; sh[j] = t2[m & 7][m >> 3]; }
        #pragma unroll
        for (int s = 0; s < 4; ++s) {
            float acc = cb3[s];
            #pragma unroll
            for (int j = 0; j < 4; ++j) acc = fmaf(sh[j], cw3[s * 4 + j], acc);
            t3[i][s] = fmaxf(acc, 0.f);
        }
    }
    float cc[4];
    #pragma unroll
    for (int c = 0; c < 4; ++c) {
        float acc = cb4[c];
        #pragma unroll
        for (int k = 0; k < 32; ++k)
            acc = fmaf(t3[k >> 2][k & 3], cw4[c * 32 + k], acc);
        cc[c] = acc;
    }
    float4 cv = {cc[0], cc[1], cc[2], cc[3]};
    ((float4*)cls_tmp)[idx] = cv;
}

// ---------------- cls mean over windows ----------------
__global__ __launch_bounds__(256) void cls_reduce_kernel(
    const float* __restrict__ cls_tmp, float* __restrict__ cls_out)
{
    const int tid = threadIdx.x;
    const int b = tid >> 2, q = tid & 3;
    float ax = 0.f, ay = 0.f, az = 0.f, aw = 0.f;
    for (int t = q; t < 512; t += 4) {
        float4 v = ((const float4*)cls_tmp)[b * 512 + t];
        ax += v.x; ay += v.y; az += v.z; aw += v.w;
    }
    ax += __shfl_xor(ax, 1); ay += __shfl_xor(ay, 1);
    az += __shfl_xor(az, 1); aw += __shfl_xor(aw, 1);
    ax += __shfl_xor(ax, 2); ay += __shfl_xor(ay, 2);
    az += __shfl_xor(az, 2); aw += __shfl_xor(aw, 2);
    if (q == 0) {
        float4 rv = {ax / 512.f, ay / 512.f, az / 512.f, aw / 512.f};
        ((float4*)cls_out)[b] = rv;
    }
}

// ---------------- avg_pool1d(k=11,s=1) with 10 zero history ----------------
__global__ __launch_bounds__(256) void pool_kernel(
    const float* __restrict__ seg, float* __restrict__ pool_out)
{
    const int idx = blockIdx.x * 256 + threadIdx.x;
    if (idx >= 64 * 8192) return;
    const int b = idx >> 13, ll = idx & 8191;
    float ax = 0.f, ay = 0.f, az = 0.f, aw = 0.f;
    int j0 = ll - 10; if (j0 < 0) j0 = 0;
    for (int j = j0; j <= ll; ++j) {
        float4 v = ((const float4*)seg)[b * 8192 + j];
        ax += v.x; ay += v.y; az += v.z; aw += v.w;
    }
    const float inv = 1.0f / 11.0f;
    float4 ov = {ax * inv, ay * inv, az * inv, aw * inv};
    ((float4*)pool_out)[idx] = ov;
}

extern "C" void kernel_launch(void* const* d_in, const int* in_sizes, int n_in,
                              void* d_out, int out_size, void* d_ws, size_t ws_size,
                              hipStream_t stream)
{
    const float* x    = (const float*)d_in[0];
    const float* h0   = (const float*)d_in[1];
    const float* w_ih = (const float*)d_in[2];
    const float* w_hh = (const float*)d_in[3];
    const float* bihp = (const float*)d_in[4];
    const float* bhhp = (const float*)d_in[5];
    const float* aw1  = (const float*)d_in[6];
    const float* aw2  = (const float*)d_in[7];
    const float* aw3  = (const float*)d_in[8];
    const float* aw4  = (const float*)d_in[9];
    const float* sw1  = (const float*)d_in[10];
    const float* sb1  = (const float*)d_in[11];
    const float* sw2  = (const float*)d_in[12];
    const float* sb2  = (const float*)d_in[13];
    const float* sw3  = (const float*)d_in[14];
    const float* sb3  = (const float*)d_in[15];
    const float* sw4  = (const float*)d_in[16];
    const float* sb4  = (const float*)d_in[17];
    const float* cw1  = (const float*)d_in[18];
    const float* cb1  = (const float*)d_in[19];
    const float* cw2  = (const float*)d_in[20];
    const float* cb2  = (const float*)d_in[21];
    const float* cw3  = (const float*)d_in[22];
    const float* cb3  = (const float*)d_in[23];
    const float* cw4  = (const float*)d_in[24];
    const float* cb4  = (const float*)d_in[25];

    float* out      = (float*)d_out;
    float* pool_out = out;                 // (64,8192,4)
    float* cls_out  = out + 2097152;       // (64,4)
    float* ys_out   = out + 2097408;       // (64,512,64)
    float* hfin     = out + 4194560;       // (8,64,64)
    float* seg_out  = out + 4227328;       // (64,8192,4)
    float* cls_tmp  = pool_out;            // staged in pool region, overwritten last

    unsigned* flags  = (unsigned*)d_ws;                        // 32 KB header
    u16*      Abf    = (u16*)((char*)d_ws + 32768);            // 8x128x128 bf16 = 256 KB
    unsigned* ring32 = (unsigned*)((char*)d_ws + 32768 + 262144);

    size_t hdr = 32768 + 262144;
    size_t slots = (ws_size > hdr) ? (ws_size - hdr) / (56ull * 256 * 4) : 8;
    int D = 512;
    if (slots < 512) {
        D = 8;
        while ((size_t)(D * 2) <= slots && D < 512) D <<= 1;
    }

    init_flags<<<32, 256, 0, stream>>>(flags);
    prep_A<<<8, 128, 0, stream>>>(aw1, aw2, aw3, Abf);
    rnn_kernel<<<64, 256, 0, stream>>>(x, h0, w_ih, w_hh, bihp, bhhp,
                                       Abf, aw4, ys_out, hfin,
                                       flags, ring32, D);
    heads_kernel<<<128, 256, 0, stream>>>(ys_out, sw1, sb1, sw2, sb2, sw3, sb3, sw4, sb4,
                                          cw1, cb1, cw2, cb2, cw3, cb3, cw4, cb4,
                                          seg_out, cls_tmp);
    cls_reduce_kernel<<<1, 256, 0, stream>>>(cls_tmp, cls_out);
    pool_kernel<<<2048, 256, 0, stream>>>(seg_out, pool_out);
}